// Round 2
// baseline (15577.397 us; speedup 1.0000x reference)
//
#include <hip/hip_runtime.h>

// ---------- types ----------
typedef _Float16 h8 __attribute__((ext_vector_type(8)));
typedef _Float16 h4 __attribute__((ext_vector_type(4)));
typedef float    f4 __attribute__((ext_vector_type(4)));

#define NBLK 256   // persistent grid = 256 blocks = 1 per CU

__device__ __forceinline__ float sigm(float x) {
    return 1.0f / (1.0f + __expf(-x));
}
__device__ __forceinline__ float tanh_fast(float x) {
    return 1.0f - 2.0f / (__expf(2.0f * x) + 1.0f);   // saturates correctly at +/-inf
}

// Two-level grid barrier: 8 group counters (32 blocks each) -> 1 root.
// Monotonic across steps; counters zeroed by prep each launch.
__device__ __forceinline__ void gridbar(unsigned* grp, unsigned* root, unsigned barno) {
    __threadfence();   // release: h stores visible before arrival
    __syncthreads();
    if (threadIdx.x == 0) {
        const int g = blockIdx.x & 7;
        unsigned old = __hip_atomic_fetch_add(&grp[g * 64], 1u, __ATOMIC_ACQ_REL,
                                              __HIP_MEMORY_SCOPE_AGENT);
        if ((old & 31u) == 31u)   // 32nd arrival of this round in this group
            __hip_atomic_fetch_add(root, 1u, __ATOMIC_ACQ_REL, __HIP_MEMORY_SCOPE_AGENT);
        const unsigned tgt = (barno + 1u) * 8u;
        unsigned spins = 0;
        while (__hip_atomic_load(root, __ATOMIC_ACQUIRE, __HIP_MEMORY_SCOPE_AGENT) < tgt) {
            __builtin_amdgcn_s_sleep(2);
            if (++spins > (1u << 24)) break;   // safety valve: corrupt-but-return
        }
    }
    __syncthreads();
    __threadfence();   // acquire: don't read stale remote h
}

// ---------- prep: zero counters + hb0, fp32 x -> fp16 ----------
__global__ void prep_kernel(const float* __restrict__ x, _Float16* __restrict__ xbuf,
                            unsigned* __restrict__ ctr, unsigned* __restrict__ hb0u) {
    const int gtid = blockIdx.x * blockDim.x + threadIdx.x;
    if (gtid < 1024) ctr[gtid] = 0u;          // grp[8] + root (4 KB region)
    if (gtid < 65536) hb0u[gtid] = 0u;        // hb0: 128x1024 fp16 = 256 KB
    const f4* src = (const f4*)x;
    h4* dst = (h4*)xbuf;
    const int stride = gridDim.x * blockDim.x;    // 524288
    for (int i = gtid; i < 8388608; i += stride)  // T*B*D/4
        dst[i] = __builtin_convertvector(src[i], h4);
}

// ---------- persistent LSTM ----------
// 256 blocks x 256 threads. Block b: mg = b>>7 (rows mg*64..+63), ug = b&127,
// units u0 = ug*8 .. +7, all 4 gates -> 32 preact cols (2 MFMA n-tiles).
// Preact col c (0..31): gate = c>>3 (f,i,g,o), unit = c&7.
// x-half W (K 0..1023): per-wave B-fragments cached in 256 VGPRs.
// h-half W (K 1024..2047): LDS, conflict-free chunk layout:
//   f16 index = kc*1024 + col*32 + quad*8 + j   (kc = k/32 within h-half)
__global__ __launch_bounds__(256, 1)
void lstm_kernel(const _Float16* __restrict__ xbuf,
                 _Float16* __restrict__ hb0, _Float16* __restrict__ hb1,
                 const float* __restrict__ Wf, const float* __restrict__ bfp,
                 const float* __restrict__ Wi, const float* __restrict__ bip,
                 const float* __restrict__ Wg, const float* __restrict__ bgp,
                 const float* __restrict__ Wo, const float* __restrict__ bop,
                 float* __restrict__ out,
                 unsigned* __restrict__ grp, unsigned* __restrict__ root) {
    __shared__ _Float16 wsm[32 * 1024];   // 64 KB: h-half W, chunked

    const int tid = threadIdx.x;
    const int bid = blockIdx.x;
    const int mg = bid >> 7;
    const int ug = bid & 127;
    const int u0 = ug << 3;

    const float* WSEL[4] = {Wf, Wi, Wg, Wo};

    // ---- stage h-half W slice (32 cols x 1024 k) fp32 -> fp16 LDS, chunked ----
    {
        const int col = tid & 31;                  // preact col
        const int kseg = tid >> 5;                 // 0..7, 128 k each
        const float* srcp = WSEL[col >> 3] + (size_t)(u0 + (col & 7)) * 2048 + 1024
                          + kseg * 128;
        const int colo = col * 32;
#pragma unroll 8
        for (int k4 = 0; k4 < 128; k4 += 4) {
            const int k = kseg * 128 + k4;
            f4 v = *(const f4*)(srcp + k4);
            h4 hv = __builtin_convertvector(v, h4);
            *(h4*)&wsm[(k >> 5) * 1024 + colo + ((k >> 3) & 3) * 8 + (k & 7)] = hv;
        }
    }

    // ---- per-lane constants ----
    const int lane  = tid & 63;
    const int wv    = tid >> 6;        // wave -> m-strip
    const int row16 = lane & 15;
    const int quad  = lane >> 4;
    const int uu    = lane & 7;

    // ---- stage x-half W B-fragments into registers (64 frags = 256 VGPRs) ----
    h8 wx[64];   // [kc*2 + tile]
#pragma unroll
    for (int kc = 0; kc < 32; ++kc) {
#pragma unroll
        for (int tile = 0; tile < 2; ++tile) {
            const int col = tile * 16 + row16;
            const float* p = WSEL[col >> 3] + (size_t)(u0 + (col & 7)) * 2048
                           + kc * 32 + quad * 8;
            f4 v0 = *(const f4*)p;
            f4 v1 = *(const f4*)(p + 4);
            h4 a = __builtin_convertvector(v0, h4);
            h4 b = __builtin_convertvector(v1, h4);
            wx[kc * 2 + tile] = __builtin_shufflevector(a, b, 0, 1, 2, 3, 4, 5, 6, 7);
        }
    }
    __syncthreads();   // LDS W ready (block-local; prep finished via stream order)

    const float bias_f = bfp[u0 + uu];
    const float bias_i = bip[u0 + uu];
    const float bias_g = bgp[u0 + uu];
    const float bias_o = bop[u0 + uu];

    const int zrow = mg * 64 + wv * 16 + row16;
    const int boff = row16 * 32 + quad * 8;       // LDS B-frag base (f16 units), tile1 +512
    const int drow = mg * 64 + wv * 16 + quad * 4;
    const bool writer = (lane & 8) == 0;
    const bool himask = (lane & 8) != 0;

    const _Float16* hbv[2] = {hb0, hb1};
    const _Float16* xbase = xbuf + (size_t)zrow * 1024 + quad * 8;

    float cc[4] = {0.f, 0.f, 0.f, 0.f};

    for (int t = 0; t < 256; ++t) {
        const _Float16* xA = xbase + (size_t)t * 131072;
        const _Float16* hA = hbv[t & 1] + (size_t)zrow * 1024 + quad * 8;
        _Float16* hw = (_Float16*)hbv[(t + 1) & 1];

        f4 a00 = {0.f,0.f,0.f,0.f}, a01 = {0.f,0.f,0.f,0.f};
        f4 a10 = {0.f,0.f,0.f,0.f}, a11 = {0.f,0.f,0.f,0.f};

        // x half: A from global fp16, B from registers
#pragma unroll
        for (int kc = 0; kc < 32; kc += 2) {
            h8 av0 = *(const h8*)(xA + kc * 32);
            h8 av1 = *(const h8*)(xA + kc * 32 + 32);
            a00 = __builtin_amdgcn_mfma_f32_16x16x32_f16(av0, wx[kc*2+0], a00, 0, 0, 0);
            a10 = __builtin_amdgcn_mfma_f32_16x16x32_f16(av0, wx[kc*2+1], a10, 0, 0, 0);
            a01 = __builtin_amdgcn_mfma_f32_16x16x32_f16(av1, wx[kc*2+2], a01, 0, 0, 0);
            a11 = __builtin_amdgcn_mfma_f32_16x16x32_f16(av1, wx[kc*2+3], a11, 0, 0, 0);
        }
        // h half: A from double-buffered global fp16, B from LDS (conflict-free)
#pragma unroll
        for (int kc = 0; kc < 32; kc += 2) {
            h8 av0 = *(const h8*)(hA + kc * 32);
            h8 av1 = *(const h8*)(hA + kc * 32 + 32);
            h8 b00 = *(const h8*)&wsm[kc * 1024 + boff];
            h8 b10 = *(const h8*)&wsm[kc * 1024 + boff + 512];
            h8 b01 = *(const h8*)&wsm[(kc + 1) * 1024 + boff];
            h8 b11 = *(const h8*)&wsm[(kc + 1) * 1024 + boff + 512];
            a00 = __builtin_amdgcn_mfma_f32_16x16x32_f16(av0, b00, a00, 0, 0, 0);
            a10 = __builtin_amdgcn_mfma_f32_16x16x32_f16(av0, b10, a10, 0, 0, 0);
            a01 = __builtin_amdgcn_mfma_f32_16x16x32_f16(av1, b01, a01, 0, 0, 0);
            a11 = __builtin_amdgcn_mfma_f32_16x16x32_f16(av1, b11, a11, 0, 0, 0);
        }

        // ---- epilogue: gather gate pairs, activations, state update ----
        f4 s0 = a00 + a01;   // tile0: f|i preacts, col = lane&15
        f4 s1 = a10 + a11;   // tile1: g|o preacts
        float q0[4], q1[4];
#pragma unroll
        for (int j = 0; j < 4; ++j) {
            q0[j] = __shfl_xor(s0[j], 8, 64);
            q1[j] = __shfl_xor(s1[j], 8, 64);
        }
        float* outb = out + (size_t)t * 131072;
#pragma unroll
        for (int j = 0; j < 4; ++j) {
            float pf = himask ? q0[j] : s0[j];
            float pi = himask ? s0[j] : q0[j];
            float pg = himask ? q1[j] : s1[j];
            float po = himask ? s1[j] : q1[j];
            float fg = sigm(pf + bias_f);
            float ig = sigm(pi + bias_i);
            float gg = tanh_fast(pg + bias_g);
            float og = sigm(po + bias_o);
            float cn = fg * cc[j] + ig * gg;
            cc[j] = cn;
            float hn = og * tanh_fast(cn);
            if (writer) {
                const size_t o = (size_t)(drow + j) * 1024 + u0 + uu;
                hw[o] = (_Float16)hn;            // feedback for step t+1
                outb[o] = hn;                    // outputs[t]
                if (t == 255) out[33554432 + o] = hn;   // hx
            }
        }
        if (t < 255) gridbar(grp, root, (unsigned)t);
    }
    // cx
    if (writer) {
#pragma unroll
        for (int j = 0; j < 4; ++j)
            out[33554432 + 131072 + (size_t)(drow + j) * 1024 + u0 + uu] = cc[j];
    }
}

extern "C" void kernel_launch(void* const* d_in, const int* in_sizes, int n_in,
                              void* d_out, int out_size, void* d_ws, size_t ws_size,
                              hipStream_t stream) {
    const float* x  = (const float*)d_in[0];
    const float* Wf = (const float*)d_in[1];
    const float* bf = (const float*)d_in[2];
    const float* Wi = (const float*)d_in[3];
    const float* bi = (const float*)d_in[4];
    const float* Wg = (const float*)d_in[5];
    const float* bg = (const float*)d_in[6];
    const float* Wo = (const float*)d_in[7];
    const float* bo = (const float*)d_in[8];
    float* out = (float*)d_out;

    unsigned char* ws = (unsigned char*)d_ws;
    unsigned* grp  = (unsigned*)ws;                       // 8 counters, 256-B stride
    unsigned* root = (unsigned*)(ws + 2048);
    _Float16* hb0  = (_Float16*)(ws + 4096);              // 128x1024 fp16 (256 KB)
    _Float16* hb1  = (_Float16*)(ws + 4096 + 262144);
    _Float16* xbuf = (_Float16*)(ws + 4096 + 524288);     // 256x128x1024 fp16 (64 MB)

    prep_kernel<<<2048, 256, 0, stream>>>(x, xbuf, grp, (unsigned*)hb0);
    lstm_kernel<<<NBLK, 256, 0, stream>>>(xbuf, hb0, hb1,
                                          Wf, bf, Wi, bi, Wg, bg, Wo, bo,
                                          out, grp, root);
}

// Round 3
// 5135.940 us; speedup vs baseline: 3.0330x; 3.0330x over previous
//
#include <hip/hip_runtime.h>

// ---------- types ----------
typedef _Float16 h8 __attribute__((ext_vector_type(8)));
typedef _Float16 h4 __attribute__((ext_vector_type(4)));
typedef float    f4 __attribute__((ext_vector_type(4)));

#define NBLK 256   // persistent grid = 256 blocks = 1 per CU

__device__ __forceinline__ float sigm(float x) {
    return 1.0f / (1.0f + __expf(-x));
}
__device__ __forceinline__ float tanh_fast(float x) {
    return 1.0f - 2.0f / (__expf(2.0f * x) + 1.0f);   // saturates correctly at +/-inf
}

// Grid barrier, fence-hygienic for CDNA4 non-coherent per-XCD L2:
//   - arrival + spin use RELAXED agent atomics (no per-poll buffer_inv!)
//   - exactly ONE release fence (buffer_wbl2) before arrival and ONE acquire
//     fence (buffer_inv) after the spin, per block per step, on tid 0 only
//     (wbl2/inv are L2-wide cache-maintenance ops).
// Two-level: 8 group counters (32 blocks each, 256-B apart) -> 1 root.
__device__ __forceinline__ void gridbar(unsigned* grp, unsigned* root, unsigned barno) {
    __syncthreads();   // all waves' h/out stores acked to L2 (vmcnt(0) before s_barrier)
    if (threadIdx.x == 0) {
        __builtin_amdgcn_fence(__ATOMIC_RELEASE, "agent");   // flush dirty L2 lines once
        const int g = blockIdx.x & 7;
        unsigned old = __hip_atomic_fetch_add(&grp[g * 64], 1u, __ATOMIC_RELAXED,
                                              __HIP_MEMORY_SCOPE_AGENT);
        if ((old & 31u) == 31u)   // 32nd arrival of this round in this group
            __hip_atomic_fetch_add(root, 1u, __ATOMIC_RELAXED, __HIP_MEMORY_SCOPE_AGENT);
        const unsigned tgt = (barno + 1u) * 8u;
        unsigned spins = 0;
        while (__hip_atomic_load(root, __ATOMIC_RELAXED, __HIP_MEMORY_SCOPE_AGENT) < tgt) {
            __builtin_amdgcn_s_sleep(2);
            if (++spins > (1u << 24)) break;   // safety valve: corrupt-but-return
        }
        __builtin_amdgcn_fence(__ATOMIC_ACQUIRE, "agent");   // drop stale L2 lines once
    }
    __syncthreads();
}

// ---------- prep: zero counters + hb0, fp32 x -> fp16 ----------
__global__ void prep_kernel(const float* __restrict__ x, _Float16* __restrict__ xbuf,
                            unsigned* __restrict__ ctr, unsigned* __restrict__ hb0u) {
    const int gtid = blockIdx.x * blockDim.x + threadIdx.x;
    if (gtid < 1024) ctr[gtid] = 0u;          // grp[8] (256-B stride) + root
    if (gtid < 65536) hb0u[gtid] = 0u;        // hb0: 128x1024 fp16 = 256 KB
    const f4* src = (const f4*)x;
    h4* dst = (h4*)xbuf;
    const int stride = gridDim.x * blockDim.x;    // 524288
    for (int i = gtid; i < 8388608; i += stride)  // T*B*D/4
        dst[i] = __builtin_convertvector(src[i], h4);
}

// ---------- persistent LSTM ----------
// 256 blocks x 256 threads. Block b: mg = b>>7 (rows mg*64..+63), ug = b&127,
// units u0 = ug*8 .. +7, all 4 gates -> 32 preact cols (2 MFMA n-tiles).
// Preact col c (0..31): gate = c>>3 (f,i,g,o), unit = c&7.
// ALL of W (K=2048) in LDS, conflict-free chunk layout:
//   f16 idx = kc*1024 + tile*512 + quad*128 + row16*8 + j
//   (kc = k>>5, quad = (k>>3)&3, j = k&7, col = tile*16 + row16)
// Read addr for lane L (= quad*16+row16): byte = kc*2048 + tile*1024 + L*16
//   -> perfectly contiguous 16 B/lane -> zero bank conflicts.
__global__ __launch_bounds__(256, 1)
void lstm_kernel(const _Float16* __restrict__ xbuf,
                 _Float16* __restrict__ hb0, _Float16* __restrict__ hb1,
                 const float* __restrict__ Wf, const float* __restrict__ bfp,
                 const float* __restrict__ Wi, const float* __restrict__ bip,
                 const float* __restrict__ Wg, const float* __restrict__ bgp,
                 const float* __restrict__ Wo, const float* __restrict__ bop,
                 float* __restrict__ out,
                 unsigned* __restrict__ grp, unsigned* __restrict__ root) {
    __shared__ _Float16 wsm[64 * 1024];   // 128 KB: full W slice, chunked

    const int tid = threadIdx.x;
    const int bid = blockIdx.x;
    const int mg = bid >> 7;
    const int ug = bid & 127;
    const int u0 = ug << 3;

    const float* WSEL[4] = {Wf, Wi, Wg, Wo};

    // ---- stage W slice (32 cols x 2048 k) fp32 -> fp16 LDS, chunked ----
    {
        const int col = tid & 31;                  // preact col
        const int kseg = tid >> 5;                 // 0..7, 256 k each
        const float* srcp = WSEL[col >> 3] + (size_t)(u0 + (col & 7)) * 2048
                          + kseg * 256;
        const int cbase = (col >> 4) * 512 + (col & 15) * 8;
#pragma unroll 8
        for (int k4 = 0; k4 < 256; k4 += 4) {
            const int k = kseg * 256 + k4;
            f4 v = *(const f4*)(srcp + k4);
            h4 hv = __builtin_convertvector(v, h4);
            *(h4*)&wsm[(k >> 5) * 1024 + cbase + ((k >> 3) & 3) * 128 + (k & 7)] = hv;
        }
    }

    // ---- per-lane constants ----
    const int lane  = tid & 63;
    const int wv    = tid >> 6;        // wave -> m-strip
    const int row16 = lane & 15;
    const int quad  = lane >> 4;
    const int uu    = lane & 7;

    __syncthreads();   // W staged (block-local)

    const float bias_f = bfp[u0 + uu];
    const float bias_i = bip[u0 + uu];
    const float bias_g = bgp[u0 + uu];
    const float bias_o = bop[u0 + uu];

    const int zrow = mg * 64 + wv * 16 + row16;
    const int boff = quad * 128 + row16 * 8;      // lane*8 f16 = lane*16 B
    const int drow = mg * 64 + wv * 16 + quad * 4;
    const bool writer = (lane & 8) == 0;
    const bool himask = (lane & 8) != 0;

    const _Float16* hbv[2] = {hb0, hb1};
    const size_t aoff = (size_t)zrow * 1024 + quad * 8;
    const _Float16* xbase = xbuf + aoff;

    float cc[4] = {0.f, 0.f, 0.f, 0.f};

    for (int t = 0; t < 256; ++t) {
        const _Float16* xA = xbase + (size_t)t * 131072;
        const _Float16* hA = hbv[t & 1] + aoff;
        _Float16* hw = (_Float16*)hbv[(t + 1) & 1];

        f4 a00 = {0.f,0.f,0.f,0.f}, a01 = {0.f,0.f,0.f,0.f};
        f4 a10 = {0.f,0.f,0.f,0.f}, a11 = {0.f,0.f,0.f,0.f};

        // x half: k chunks 0..31
#pragma unroll
        for (int kc = 0; kc < 32; kc += 2) {
            h8 av0 = *(const h8*)(xA + kc * 32);
            h8 av1 = *(const h8*)(xA + kc * 32 + 32);
            h8 b00 = *(const h8*)&wsm[kc * 1024 + boff];
            h8 b10 = *(const h8*)&wsm[kc * 1024 + boff + 512];
            h8 b01 = *(const h8*)&wsm[(kc + 1) * 1024 + boff];
            h8 b11 = *(const h8*)&wsm[(kc + 1) * 1024 + boff + 512];
            a00 = __builtin_amdgcn_mfma_f32_16x16x32_f16(av0, b00, a00, 0, 0, 0);
            a10 = __builtin_amdgcn_mfma_f32_16x16x32_f16(av0, b10, a10, 0, 0, 0);
            a01 = __builtin_amdgcn_mfma_f32_16x16x32_f16(av1, b01, a01, 0, 0, 0);
            a11 = __builtin_amdgcn_mfma_f32_16x16x32_f16(av1, b11, a11, 0, 0, 0);
        }
        // h half: k chunks 32..63
#pragma unroll
        for (int kc = 32; kc < 64; kc += 2) {
            h8 av0 = *(const h8*)(hA + (kc - 32) * 32);
            h8 av1 = *(const h8*)(hA + (kc - 32) * 32 + 32);
            h8 b00 = *(const h8*)&wsm[kc * 1024 + boff];
            h8 b10 = *(const h8*)&wsm[kc * 1024 + boff + 512];
            h8 b01 = *(const h8*)&wsm[(kc + 1) * 1024 + boff];
            h8 b11 = *(const h8*)&wsm[(kc + 1) * 1024 + boff + 512];
            a00 = __builtin_amdgcn_mfma_f32_16x16x32_f16(av0, b00, a00, 0, 0, 0);
            a10 = __builtin_amdgcn_mfma_f32_16x16x32_f16(av0, b10, a10, 0, 0, 0);
            a01 = __builtin_amdgcn_mfma_f32_16x16x32_f16(av1, b01, a01, 0, 0, 0);
            a11 = __builtin_amdgcn_mfma_f32_16x16x32_f16(av1, b11, a11, 0, 0, 0);
        }

        // ---- epilogue: gather gate pairs, activations, state update ----
        f4 s0 = a00 + a01;   // tile0: f|i preacts, col = lane&15
        f4 s1 = a10 + a11;   // tile1: g|o preacts
        float q0[4], q1[4];
#pragma unroll
        for (int j = 0; j < 4; ++j) {
            q0[j] = __shfl_xor(s0[j], 8, 64);
            q1[j] = __shfl_xor(s1[j], 8, 64);
        }
        float* outb = out + (size_t)t * 131072;
#pragma unroll
        for (int j = 0; j < 4; ++j) {
            float pf = himask ? q0[j] : s0[j];
            float pi = himask ? s0[j] : q0[j];
            float pg = himask ? q1[j] : s1[j];
            float po = himask ? s1[j] : q1[j];
            float fg = sigm(pf + bias_f);
            float ig = sigm(pi + bias_i);
            float gg = tanh_fast(pg + bias_g);
            float og = sigm(po + bias_o);
            float cn = fg * cc[j] + ig * gg;
            cc[j] = cn;
            float hn = og * tanh_fast(cn);
            if (writer) {
                const size_t o = (size_t)(drow + j) * 1024 + u0 + uu;
                hw[o] = (_Float16)hn;            // feedback for step t+1
                outb[o] = hn;                    // outputs[t]
                if (t == 255) out[33554432 + o] = hn;   // hx
            }
        }
        if (t < 255) gridbar(grp, root, (unsigned)t);
    }
    // cx
    if (writer) {
#pragma unroll
        for (int j = 0; j < 4; ++j)
            out[33554432 + 131072 + (size_t)(drow + j) * 1024 + u0 + uu] = cc[j];
    }
}

extern "C" void kernel_launch(void* const* d_in, const int* in_sizes, int n_in,
                              void* d_out, int out_size, void* d_ws, size_t ws_size,
                              hipStream_t stream) {
    const float* x  = (const float*)d_in[0];
    const float* Wf = (const float*)d_in[1];
    const float* bf = (const float*)d_in[2];
    const float* Wi = (const float*)d_in[3];
    const float* bi = (const float*)d_in[4];
    const float* Wg = (const float*)d_in[5];
    const float* bg = (const float*)d_in[6];
    const float* Wo = (const float*)d_in[7];
    const float* bo = (const float*)d_in[8];
    float* out = (float*)d_out;

    unsigned char* ws = (unsigned char*)d_ws;
    unsigned* grp  = (unsigned*)ws;                       // 8 counters, 256-B stride
    unsigned* root = (unsigned*)(ws + 2048);
    _Float16* hb0  = (_Float16*)(ws + 4096);              // 128x1024 fp16 (256 KB)
    _Float16* hb1  = (_Float16*)(ws + 4096 + 262144);
    _Float16* xbuf = (_Float16*)(ws + 4096 + 524288);     // 256x128x1024 fp16 (64 MB)

    prep_kernel<<<2048, 256, 0, stream>>>(x, xbuf, grp, (unsigned*)hb0);
    lstm_kernel<<<NBLK, 256, 0, stream>>>(xbuf, hb0, hb1,
                                          Wf, bf, Wi, bi, Wg, bg, Wo, bo,
                                          out, grp, root);
}